// Round 10
// baseline (139.786 us; speedup 1.0000x reference)
//
#include <hip/hip_runtime.h>
#include <math.h>

constexpr int IN_C = 31;
constexpr int TOT  = 44;
constexpr int HW   = 256 * 256;
constexpr int NPIX = 4 * HW;
constexpr float SMIN = 0.001f, SMAX = 1000.0f;
constexpr float PI_F = 3.14159265358979323846f;

__device__ __forceinline__ float frcp(float v) { return __builtin_amdgcn_rcpf(v); }

// Post-GEMV pipeline for ONE pixel: m store, scales, Givens R, S = R^T D R,
// two-phase stage+flush through 8KB/wave LDS (wave-synchronous, no barriers).
__device__ __forceinline__ void finish_pixel(
    const float* __restrict__ acc,   // 44 encoder outputs for this pixel
    float4* __restrict__ wbuf4,      // per-wave LDS staging, 512 float4 (8 KB)
    float* __restrict__ out,
    int pix, int lane, size_t pixbase4)
{
    // ---- m ----
    float4* mp = reinterpret_cast<float4*>(out + (size_t)pix * 8);
    mp[0] = make_float4(acc[0], acc[1], acc[2], acc[3]);
    mp[1] = make_float4(acc[4], acc[5], acc[6], acc[7]);

    // ---- sqrt scales (rcp-based sigmoid) ----
    float sq[8];
#pragma unroll
    for (int j = 0; j < 8; ++j) {
        const float sig = frcp(1.0f + __expf(-acc[8 + j]));
        const float s   = fmaf(SMAX - SMIN, sig, SMIN);
        sq[j] = __builtin_amdgcn_sqrtf(s);
    }

    // ---- R from Givens chain (identity const-folded by full unroll) ----
    float R[8][8];
#pragma unroll
    for (int i = 0; i < 8; ++i)
#pragma unroll
        for (int k = 0; k < 8; ++k) R[i][k] = (i == k) ? 1.0f : 0.0f;

    int cc = 0;
#pragma unroll
    for (int i = 0; i < 7; ++i) {
#pragma unroll
        for (int j = i + 1; j < 8; ++j) {
            const float wv = acc[16 + cc];
            // tanh(wv) = 1 - 2/(e^{2wv}+1); saturates correctly for large |wv|
            const float th = fmaf(-2.0f, frcp(__expf(2.0f * wv) + 1.0f), 1.0f);
            const float a  = PI_F * th;
            const float cs = __cosf(a);
            const float ss = __sinf(a);
#pragma unroll
            for (int r = 0; r < 8; ++r) {
                const float ri = R[r][i];
                const float rj = R[r][j];
                R[r][i] = fmaf(ri, cs, rj * ss);
                R[r][j] = fmaf(rj, cs, -(ri * ss));
            }
            ++cc;
        }
    }

    // scale row j by sqrt(s_j):  S = (sqrtD R)^T (sqrtD R)
#pragma unroll
    for (int j = 0; j < 8; ++j)
#pragma unroll
        for (int k = 0; k < 8; ++k) R[j][k] *= sq[j];

    float S[8][8];
#pragma unroll
    for (int i = 0; i < 8; ++i)
#pragma unroll
        for (int k = i; k < 8; ++k) {
            float d = 0.0f;
#pragma unroll
            for (int j = 0; j < 8; ++j) d = fmaf(R[j][i], R[j][k], d);
            S[i][k] = d; S[k][i] = d;
        }

    // ---- two-phase staged flush (swizzle v ^ (lane&7), bank-clean) ----
    float4* S4 = reinterpret_cast<float4*>(out + (size_t)NPIX * 8);
#pragma unroll
    for (int p = 0; p < 2; ++p) {
#pragma unroll
        for (int r = 0; r < 4; ++r) {
            const int i  = 4 * p + r;
            const int v0 = r * 2;
            const int v1 = v0 + 1;
            wbuf4[lane * 8 + (v0 ^ (lane & 7))] =
                make_float4(S[i][0], S[i][1], S[i][2], S[i][3]);
            wbuf4[lane * 8 + (v1 ^ (lane & 7))] =
                make_float4(S[i][4], S[i][5], S[i][6], S[i][7]);
        }
#pragma unroll
        for (int k = 0; k < 8; ++k) {
            const int t  = k * 64 + lane;
            const int pl = t >> 3;           // local pixel 0..63
            const int v  = t & 7;            // float4 index within half
            S4[pixbase4 + (size_t)pl * 16 + p * 8 + v] =
                wbuf4[pl * 8 + (v ^ (pl & 7))];
        }
    }
}

// 2 pixels/thread, SEQUENTIAL (GEMV A -> finish A -> GEMV B -> finish B) so
// the two accumulator sets are never simultaneously live (R8's spill cause).
// xB loads issued at the top: in flight across all of finish A (~3k cycles).
// __launch_bounds__(256,1): VGPR cap 512, no artificial 128 ceiling.
__global__ __launch_bounds__(256, 1) void sepgpd_fused(
    const float* __restrict__ x,
    const float* __restrict__ Wenc,
    const float* __restrict__ benc,
    float* __restrict__ out)
{
    __shared__ float4 stg[4][512];       // 32 KB: 4 waves x 8 KB S-staging

    const int tid  = threadIdx.x;
    const int lane = tid & 63;
    const int wid  = tid >> 6;
    const int W0   = blockIdx.x * 512 + wid * 128;  // wave's first pixel
    const int pA   = W0 + lane;
    const int pB   = pA + 64;
    const int b    = pA >> 16;                      // 512 | 65536: same image
    const int hwA  = pA & (HW - 1);

    const float* xp = x + (size_t)b * IN_C * HW + hwA;

    // ---- all 62 x loads issued up front, in flight together ----
    float xA[IN_C], xB[IN_C];
#pragma unroll
    for (int c = 0; c < IN_C; ++c) xA[c] = xp[(size_t)c * HW];
#pragma unroll
    for (int c = 0; c < IN_C; ++c) xB[c] = xp[(size_t)c * HW + 64];

    float4* wbuf4 = &stg[wid][0];

    // ---- pixel A: GEMV (contiguous weight rows -> s_load batches) ----
    float acc[TOT];
#pragma unroll
    for (int o = 0; o < TOT; ++o) {
        float a = benc[o];
#pragma unroll
        for (int c = 0; c < IN_C; ++c)
            a = fmaf(xA[c], Wenc[o * IN_C + c], a);
        acc[o] = a;
    }
    finish_pixel(acc, wbuf4, out, pA, lane, (size_t)W0 * 16);

    // ---- pixel B (xB latency hidden under finish A) ----
#pragma unroll
    for (int o = 0; o < TOT; ++o) {
        float a = benc[o];
#pragma unroll
        for (int c = 0; c < IN_C; ++c)
            a = fmaf(xB[c], Wenc[o * IN_C + c], a);
        acc[o] = a;
    }
    finish_pixel(acc, wbuf4, out, pB, lane, (size_t)(W0 + 64) * 16);
}

extern "C" void kernel_launch(void* const* d_in, const int* in_sizes, int n_in,
                              void* d_out, int out_size, void* d_ws, size_t ws_size,
                              hipStream_t stream)
{
    const float* x    = (const float*)d_in[0];
    const float* Wenc = (const float*)d_in[1];
    const float* benc = (const float*)d_in[2];
    float* out        = (float*)d_out;

    dim3 grid(NPIX / 512), block(256);
    sepgpd_fused<<<grid, block, 0, stream>>>(x, Wenc, benc, out);
}

// Round 11
// 34.629 us; speedup vs baseline: 4.0367x; 4.0367x over previous
//
#include <hip/hip_runtime.h>
#include <math.h>

constexpr int IN_C = 31;
constexpr int TOT  = 44;
constexpr int HW   = 256 * 256;
constexpr int NPIX = 4 * HW;
constexpr float SMIN = 0.001f, SMAX = 1000.0f;
constexpr float PI_F = 3.14159265358979323846f;

typedef __attribute__((ext_vector_type(8))) short bf16x8;
typedef __attribute__((ext_vector_type(4))) float f32x4;

__device__ __forceinline__ float frcp(float v) { return __builtin_amdgcn_rcpf(v); }

__device__ __forceinline__ short f2bf(float f) {
    union { float f; unsigned u; } v; v.f = f;
    unsigned r = v.u + 0x7FFFu + ((v.u >> 16) & 1u);   // RNE
    return (short)(r >> 16);
}
__device__ __forceinline__ float bf2f(short h) {
    union { unsigned u; float f; } v; v.u = ((unsigned)(unsigned short)h) << 16;
    return v.f;
}

// One thread per pixel, 256 threads/block = 4 waves, wave owns 64 pixels.
// Encoder GEMV done as wave-level MFMA: X(64x32) * W^T(32x48) via 12 tiles of
// 16x16x32 bf16, 3-product split (hi*hi + lo*hi + hi*lo) for ~fp32 accuracy.
// K-layout assumption cancels (same map used for A and B); C/D layout is the
// HW-verified col=lane&15, row=(lane>>4)*4+reg.
// Post-MFMA two-phase LDS transpose ([64][34] pad, 2-way max) puts all 44
// channels in lane=pixel; buffer reused for the proven two-phase S flush.
__global__ __launch_bounds__(256, 4) void sepgpd_fused(
    const float* __restrict__ x,
    const float* __restrict__ Wenc,
    const float* __restrict__ benc,
    float* __restrict__ out)
{
    __shared__ float tbuf[4][64 * 34];   // 4 waves x 8704 B (transpose + staging)

    const int tid  = threadIdx.x;
    const int lane = tid & 63;
    const int wid  = tid >> 6;
    const int W0   = blockIdx.x * 256 + wid * 64;   // wave's first pixel
    const int b    = W0 >> 16;                      // 64 | 65536: same image
    const int hwb  = W0 & (HW - 1);
    const int lrow = lane & 15;                     // M/N lane index
    const int lgrp = lane >> 4;                     // K group

    const float* xb = x + (size_t)b * IN_C * HW + hwb;
    float* wt = &tbuf[wid][0];

    // ---- B fragments: W^T tiles (48 chans x 32 K), hi/lo bf16 split ----
    bf16x8 bhi[3], blo[3];
#pragma unroll
    for (int n = 0; n < 3; ++n) {
        const int o = n * 16 + lrow;
#pragma unroll
        for (int j = 0; j < 8; ++j) {
            const int k = lgrp * 8 + j;
            const float wv = (o < TOT && k < IN_C) ? Wenc[o * IN_C + k] : 0.0f;
            const short h = f2bf(wv);
            bhi[n][j] = h;
            blo[n][j] = f2bf(wv - bf2f(h));
        }
    }

    // ---- MFMA: 4 M-tiles x 3 N-tiles x 3 products ----
    f32x4 acc[4][3];
#pragma unroll
    for (int t = 0; t < 4; ++t)
#pragma unroll
        for (int n = 0; n < 3; ++n) acc[t][n] = (f32x4)0.0f;

#pragma unroll
    for (int t = 0; t < 4; ++t) {
        float xf[8];
#pragma unroll
        for (int j = 0; j < 8; ++j) {
            const int k = lgrp * 8 + j;
            xf[j] = (k < IN_C) ? xb[(size_t)k * HW + t * 16 + lrow] : 0.0f;
        }
        bf16x8 ahi, alo;
#pragma unroll
        for (int j = 0; j < 8; ++j) {
            const short h = f2bf(xf[j]);
            ahi[j] = h;
            alo[j] = f2bf(xf[j] - bf2f(h));
        }
#pragma unroll
        for (int n = 0; n < 3; ++n) {
            acc[t][n] = __builtin_amdgcn_mfma_f32_16x16x32_bf16(ahi, bhi[n], acc[t][n], 0, 0, 0);
            acc[t][n] = __builtin_amdgcn_mfma_f32_16x16x32_bf16(alo, bhi[n], acc[t][n], 0, 0, 0);
            acc[t][n] = __builtin_amdgcn_mfma_f32_16x16x32_bf16(ahi, blo[n], acc[t][n], 0, 0, 0);
        }
    }

    // ---- two-phase LDS transpose -> per-lane a44 (wave-synchronous) ----
    float a44[TOT];

    // phase A: chans 0..31 (n-tiles 0,1)
#pragma unroll
    for (int t = 0; t < 4; ++t)
#pragma unroll
        for (int n = 0; n < 2; ++n)
#pragma unroll
            for (int r = 0; r < 4; ++r) {
                const int p = t * 16 + lgrp * 4 + r;      // pixel (C row)
                wt[p * 34 + n * 16 + lrow] = acc[t][n][r];
            }
    {
        const float2* w2 = reinterpret_cast<const float2*>(wt + lane * 34);
#pragma unroll
        for (int q = 0; q < 16; ++q) {
            const float2 v = w2[q];
            a44[2 * q]     = v.x;
            a44[2 * q + 1] = v.y;
        }
    }
    // phase B: chans 32..43 (n-tile 2; cols reused)
#pragma unroll
    for (int t = 0; t < 4; ++t)
#pragma unroll
        for (int r = 0; r < 4; ++r) {
            const int p = t * 16 + lgrp * 4 + r;
            wt[p * 34 + lrow] = acc[t][2][r];
        }
    {
        const float2* w2 = reinterpret_cast<const float2*>(wt + lane * 34);
#pragma unroll
        for (int q = 0; q < 6; ++q) {
            const float2 v = w2[q];
            a44[32 + 2 * q]     = v.x;
            a44[32 + 2 * q + 1] = v.y;
        }
    }

    // ---- bias (uniform, scalar-cached) ----
#pragma unroll
    for (int o = 0; o < TOT; ++o) a44[o] += benc[o];

    // ---- m: first 8 channels, per-pixel contiguous ----
    const int pix = W0 + lane;
    float4* mp = reinterpret_cast<float4*>(out + (size_t)pix * 8);
    mp[0] = make_float4(a44[0], a44[1], a44[2], a44[3]);
    mp[1] = make_float4(a44[4], a44[5], a44[6], a44[7]);

    // ---- sqrt scales (rcp-based sigmoid) ----
    float sq[8];
#pragma unroll
    for (int j = 0; j < 8; ++j) {
        const float sig = frcp(1.0f + __expf(-a44[8 + j]));
        const float s   = fmaf(SMAX - SMIN, sig, SMIN);
        sq[j] = __builtin_amdgcn_sqrtf(s);
    }

    // ---- R from Givens chain (identity const-folded by full unroll) ----
    float R[8][8];
#pragma unroll
    for (int i = 0; i < 8; ++i)
#pragma unroll
        for (int k = 0; k < 8; ++k) R[i][k] = (i == k) ? 1.0f : 0.0f;

    int cc = 0;
#pragma unroll
    for (int i = 0; i < 7; ++i) {
#pragma unroll
        for (int j = i + 1; j < 8; ++j) {
            const float wv = a44[16 + cc];
            // tanh(wv) = 1 - 2/(e^{2wv}+1); saturates correctly for large |wv|
            const float th = fmaf(-2.0f, frcp(__expf(2.0f * wv) + 1.0f), 1.0f);
            const float a  = PI_F * th;
            const float cs = __cosf(a);
            const float ss = __sinf(a);
#pragma unroll
            for (int r = 0; r < 8; ++r) {
                const float ri = R[r][i];
                const float rj = R[r][j];
                R[r][i] = fmaf(ri, cs, rj * ss);
                R[r][j] = fmaf(rj, cs, -(ri * ss));
            }
            ++cc;
        }
    }

    // scale row j by sqrt(s_j):  S = (sqrtD R)^T (sqrtD R)
#pragma unroll
    for (int j = 0; j < 8; ++j)
#pragma unroll
        for (int k = 0; k < 8; ++k) R[j][k] *= sq[j];

    float S[8][8];
#pragma unroll
    for (int i = 0; i < 8; ++i)
#pragma unroll
        for (int k = i; k < 8; ++k) {
            float d = 0.0f;
#pragma unroll
            for (int j = 0; j < 8; ++j) d = fmaf(R[j][i], R[j][k], d);
            S[i][k] = d; S[k][i] = d;
        }

    // ---- two-phase staged flush of S (reuses wt; wave-synchronous) ----
    float4* wbuf4 = reinterpret_cast<float4*>(wt);
    float4* S4 = reinterpret_cast<float4*>(out + (size_t)NPIX * 8);
    const size_t pixbase4 = (size_t)W0 * 16;   // float4 units

#pragma unroll
    for (int p = 0; p < 2; ++p) {
#pragma unroll
        for (int r = 0; r < 4; ++r) {
            const int i  = 4 * p + r;
            const int v0 = r * 2;
            const int v1 = v0 + 1;
            wbuf4[lane * 8 + (v0 ^ (lane & 7))] =
                make_float4(S[i][0], S[i][1], S[i][2], S[i][3]);
            wbuf4[lane * 8 + (v1 ^ (lane & 7))] =
                make_float4(S[i][4], S[i][5], S[i][6], S[i][7]);
        }
#pragma unroll
        for (int k = 0; k < 8; ++k) {
            const int t  = k * 64 + lane;
            const int pl = t >> 3;           // local pixel 0..63
            const int v  = t & 7;            // float4 index within half
            S4[pixbase4 + (size_t)pl * 16 + p * 8 + v] =
                wbuf4[pl * 8 + (v ^ (pl & 7))];
        }
    }
}

extern "C" void kernel_launch(void* const* d_in, const int* in_sizes, int n_in,
                              void* d_out, int out_size, void* d_ws, size_t ws_size,
                              hipStream_t stream)
{
    const float* x    = (const float*)d_in[0];
    const float* Wenc = (const float*)d_in[1];
    const float* benc = (const float*)d_in[2];
    float* out        = (float*)d_out;

    dim3 grid(NPIX / 256), block(256);
    sepgpd_fused<<<grid, block, 0, stream>>>(x, Wenc, benc, out);
}